// Round 8
// baseline (260.857 us; speedup 1.0000x reference)
//
#include <hip/hip_runtime.h>

// Problem constants
#define BDIM   8
#define NPIX   250000   // 500*500
#define G1N    62500    // 250*250
#define G2N    15625    // 125*125
#define NB0    977      // ceil(NPIX/256)
#define NB1    245      // ceil(G1N/256)
#define NB2    62       // ceil(G2N/256)
#define CAP0   4096
#define CAP1   4096
#define CAPM   2048
#define CH     64
#define ACH    128
#define NHEADS 4
#define DH     32
#define KSPLIT 4

static constexpr float BN_INV    = 0.99999500003749969f;   // 1/sqrt(1+1e-5)
static constexpr float ATT_SCALE = 0.17677669529663687f;   // 1/sqrt(32)

typedef _Float16 f16x8 __attribute__((ext_vector_type(8)));
typedef float f32x4 __attribute__((ext_vector_type(4)));

// Workspace word offsets (4-byte units). Zeroed prefix: [0, E_ZEND)
static constexpr size_t E_MAP0  = 0;                                  // int [B*NPIX]
static constexpr size_t E_MAP1  = E_MAP0 + (size_t)BDIM*NPIX;         // int [B*G1N]
static constexpr size_t E_CNT   = E_MAP1 + (size_t)BDIM*G1N;          // int [32]
static constexpr size_t E_ZEND  = E_CNT + 32;
static constexpr size_t E_BC    = E_ZEND;                             // int [3][B][1024]
static constexpr size_t E_BO    = E_BC + (size_t)3*BDIM*1024;         // int [3][B][1024]
static constexpr size_t E_BM    = E_BO + (size_t)3*BDIM*1024;        // ull [3][B][1024][4]
static constexpr size_t E_LIST0 = E_BM + (size_t)3*BDIM*1024*8;      // int [B*CAP0]
static constexpr size_t E_LIST1 = E_LIST0 + (size_t)BDIM*CAP0;
static constexpr size_t E_LIST2 = E_LIST1 + (size_t)BDIM*CAP1;
static constexpr size_t E_Y0    = E_LIST2 + (size_t)BDIM*CAPM;        // f32 [B*CAP0*32]
static constexpr size_t E_Y1    = E_Y0 + (size_t)BDIM*CAP0*32;       // f32 [B*CAP1*64]
static constexpr size_t E_FE    = E_Y1 + (size_t)BDIM*CAP1*64;       // f32 [B*CAPM*64]
static constexpr size_t E_QF    = E_FE + (size_t)BDIM*CAPM*64;       // f16 [32bh][CAPM][32]
static constexpr size_t E_KF    = E_QF + (size_t)32*CAPM*32/2;
static constexpr size_t E_VT    = E_KF + (size_t)32*CAPM*32/2;       // f16 [32bh][32][CAPM]
static constexpr size_t E_PACC  = E_VT + (size_t)32*CAPM*32/2;       // f32 [32bh][CAPM][4][32]
static constexpr size_t E_PML   = E_PACC + (size_t)32*CAPM*KSPLIT*32;// f32 [32bh][CAPM][4][2]

// ---------------- deterministic compaction: count / scan / emit --------------

__device__ __forceinline__ bool act0(const float* x, int pix, int b) {
  return (pix < NPIX) && (x[(size_t)b * NPIX + pix] != 0.f);
}
__device__ __forceinline__ bool act1(const int* map0, int p, int b) {
  if (p >= G1N) return false;
  int i = p / 250, j = p - i * 250;
  const int* m = map0 + (size_t)b * NPIX + (2 * i) * 500 + 2 * j;
  return (m[0] | m[1] | m[500] | m[501]) != 0;
}
__device__ __forceinline__ bool act2(const int* map1, int p, int b) {
  if (p >= G2N) return false;
  int i = p / 125, j = p - i * 125;
  const int* m = map1 + (size_t)b * G1N + (2 * i) * 250 + 2 * j;
  return (m[0] | m[1] | m[250] | m[251]) != 0;
}

#define COUNT_BODY(ACT_EXPR)                                            \
  int idx = blockIdx.x * 256 + threadIdx.x;                             \
  int b = blockIdx.y;                                                   \
  bool act = (ACT_EXPR);                                                \
  unsigned long long mask = __ballot(act);                              \
  __shared__ int wc[4];                                                 \
  if ((threadIdx.x & 63) == 0) {                                        \
    wc[threadIdx.x >> 6] = __popcll(mask);                              \
    bm[((size_t)b * 1024 + blockIdx.x) * 4 + (threadIdx.x >> 6)] = mask;\
  }                                                                     \
  __syncthreads();                                                      \
  if (threadIdx.x == 0)                                                 \
    bcnt[b * 1024 + blockIdx.x] = wc[0] + wc[1] + wc[2] + wc[3];

__global__ void k_cnt0(const float* __restrict__ x, int* __restrict__ bcnt,
                       unsigned long long* __restrict__ bm) {
  COUNT_BODY(act0(x, idx, b))
}
__global__ void k_cnt1(const int* __restrict__ map0, int* __restrict__ bcnt,
                       unsigned long long* __restrict__ bm) {
  COUNT_BODY(act1(map0, idx, b))
}
__global__ void k_cnt2(const int* __restrict__ map1, int* __restrict__ bcnt,
                       unsigned long long* __restrict__ bm) {
  COUNT_BODY(act2(map1, idx, b))
}

// one block/image, 256 threads, shfl scan (1 barrier). nblk <= 1024.
__global__ __launch_bounds__(256) void k_scan(const int* __restrict__ bcnt,
                                              int* __restrict__ boff,
                                              int* __restrict__ cnt,
                                              int nblk, int cbase) {
  int b = blockIdx.x;
  int t = threadIdx.x;
  int base = t * 4;
  int v[4];
  int ts = 0;
#pragma unroll
  for (int u = 0; u < 4; ++u) {
    v[u] = (base + u < nblk) ? bcnt[b * 1024 + base + u] : 0;
    ts += v[u];
  }
  int lane = t & 63, w = t >> 6;
  int incl = ts;
#pragma unroll
  for (int off = 1; off < 64; off <<= 1) {
    int o = __shfl_up(incl, off, 64);
    if (lane >= off) incl += o;
  }
  __shared__ int wsum[4];
  if (lane == 63) wsum[w] = incl;
  __syncthreads();
  int woff = 0;
#pragma unroll
  for (int k = 0; k < 3; ++k) if (k < w) woff += wsum[k];
  int run = woff + incl - ts;
#pragma unroll
  for (int u = 0; u < 4; ++u) {
    if (base + u < nblk) boff[b * 1024 + base + u] = run;
    run += v[u];
  }
  if (t == 255) cnt[cbase + b] = run;
}

// emit: replay stored ballot masks (no recompute / no re-read of inputs)
#define EMIT_PROLOG                                                     \
  int idx = blockIdx.x * 256 + threadIdx.x;                             \
  int b = blockIdx.y;                                                   \
  int lane = threadIdx.x & 63;                                          \
  unsigned long long mask =                                             \
      bm[((size_t)b * 1024 + blockIdx.x) * 4 + (threadIdx.x >> 6)];     \
  bool act = (mask >> lane) & 1;                                        \
  __shared__ int wbase[4];                                              \
  if (lane == 0) wbase[threadIdx.x >> 6] = __popcll(mask);              \
  __syncthreads();                                                      \
  if (threadIdx.x == 0) {                                               \
    int s = boff[b * 1024 + blockIdx.x];                                \
    for (int w = 0; w < 4; ++w) { int c = wbase[w]; wbase[w] = s; s += c; } \
  }                                                                     \
  __syncthreads();                                                      \
  int slot = wbase[threadIdx.x >> 6] + __popcll(mask & ((1ull << lane) - 1ull));

__global__ void k_emit0(const unsigned long long* __restrict__ bm,
                        const int* __restrict__ boff,
                        int* __restrict__ map0, int* __restrict__ list0) {
  EMIT_PROLOG
  if (act && slot < CAP0) {
    list0[b * CAP0 + slot] = idx;
    map0[(size_t)b * NPIX + idx] = slot + 1;
  }
}
__global__ void k_emit1(const unsigned long long* __restrict__ bm,
                        const int* __restrict__ boff,
                        int* __restrict__ map1, int* __restrict__ list1) {
  EMIT_PROLOG
  if (act && slot < CAP1) {
    list1[b * CAP1 + slot] = idx;
    map1[(size_t)b * G1N + idx] = slot + 1;
  }
}
__global__ void k_emit2(const unsigned long long* __restrict__ bm,
                        const int* __restrict__ boff,
                        int* __restrict__ list2) {
  EMIT_PROLOG
  if (act && slot < CAPM) list2[b * CAPM + slot] = idx;
}

// ---------------- sparse convs -----------------------------------------------

__global__ void k_y0(const float* __restrict__ x, const float* __restrict__ w0,
                     const float* __restrict__ b0, const float* __restrict__ g0,
                     const float* __restrict__ be0,
                     const int* __restrict__ list0, const int* __restrict__ cnt,
                     float* __restrict__ y0) {
  int t = blockIdx.x * 256 + threadIdx.x;
  int b = t >> 17;
  int r = t & 131071;
  int slot = r >> 5, c = r & 31;
  int n = min(cnt[b], CAP0);
  if (slot >= n) return;
  int pix = list0[b * CAP0 + slot];
  int i = pix / 500, j = pix - i * 500;
  float acc = b0[c];
#pragma unroll
  for (int di = 0; di < 3; ++di) {
    int ii = i + di - 1;
    if ((unsigned)ii >= 500u) continue;
#pragma unroll
    for (int dj = 0; dj < 3; ++dj) {
      int jj = j + dj - 1;
      if ((unsigned)jj >= 500u) continue;
      acc += x[(size_t)b * NPIX + ii * 500 + jj] * w0[(di * 3 + dj) * 32 + c];
    }
  }
  float o = g0[c] * acc * BN_INV + be0[c];
  y0[((size_t)(b * CAP0) + slot) * 32 + c] = fmaxf(o, 0.f);
}

__global__ void k_y1(const float* __restrict__ y0, const float* __restrict__ w1,
                     const float* __restrict__ b1, const float* __restrict__ g1,
                     const float* __restrict__ be1,
                     const int* __restrict__ map0, const int* __restrict__ list1,
                     const int* __restrict__ cnt, float* __restrict__ y1) {
  int b = blockIdx.x >> 9;          // CAP1/8 = 512
  int sblk = blockIdx.x & 511;
  int s0 = sblk * 8;
  int n = min(cnt[BDIM + b], CAP1);
  if (s0 >= n) return;
  __shared__ float inT[4][32][8];
  for (int idx = threadIdx.x; idx < 1024; idx += 64) {
    int s = idx & 7;
    int r = idx >> 3;
    int ci = r & 31, pp = r >> 5;
    float v = 0.f;
    int sg = s0 + s;
    if (sg < n) {
      int p = list1[b * CAP1 + sg];
      int i = p / 250, j = p - i * 250;
      int sm = map0[(size_t)b * NPIX + (2 * i + (pp >> 1)) * 500 + (2 * j + (pp & 1))];
      if (sm) v = y0[((size_t)(b * CAP0) + (sm - 1)) * 32 + ci];
    }
    inT[pp][ci][s] = v;
  }
  __syncthreads();
  int co = threadIdx.x;
  float acc[8];
#pragma unroll
  for (int s = 0; s < 8; ++s) acc[s] = b1[co];
#pragma unroll 2
  for (int pp = 0; pp < 4; ++pp)
    for (int ci = 0; ci < 32; ++ci) {
      float wv = w1[((pp << 5) + ci) * 64 + co];
      float4 i0 = *(const float4*)&inT[pp][ci][0];
      float4 i1 = *(const float4*)&inT[pp][ci][4];
      acc[0] += i0.x * wv; acc[1] += i0.y * wv; acc[2] += i0.z * wv; acc[3] += i0.w * wv;
      acc[4] += i1.x * wv; acc[5] += i1.y * wv; acc[6] += i1.z * wv; acc[7] += i1.w * wv;
    }
  int smax = min(8, n - s0);
  for (int s = 0; s < smax; ++s) {
    float o = g1[co] * acc[s] * BN_INV + be1[co];
    y1[((size_t)(b * CAP1) + s0 + s) * 64 + co] = fmaxf(o, 0.f);
  }
}

__global__ void k_y2(const float* __restrict__ y1, const float* __restrict__ w2,
                     const float* __restrict__ b2, const float* __restrict__ g2,
                     const float* __restrict__ be2,
                     const int* __restrict__ map1, const int* __restrict__ list2,
                     const int* __restrict__ cnt, float* __restrict__ feats) {
  int b = blockIdx.x >> 8;          // CAPM/8 = 256
  int sblk = blockIdx.x & 255;
  int s0 = sblk * 8;
  int n = min(cnt[2 * BDIM + b], CAPM);
  if (s0 >= n) return;
  __shared__ float inT[4][64][8];
  for (int idx = threadIdx.x; idx < 2048; idx += 64) {
    int s = idx & 7;
    int r = idx >> 3;
    int ci = r & 63, pp = r >> 6;
    float v = 0.f;
    int sg = s0 + s;
    if (sg < n) {
      int p = list2[b * CAPM + sg];
      int i = p / 125, j = p - i * 125;
      int sm = map1[(size_t)b * G1N + (2 * i + (pp >> 1)) * 250 + (2 * j + (pp & 1))];
      if (sm) v = y1[((size_t)(b * CAP1) + (sm - 1)) * 64 + ci];
    }
    inT[pp][ci][s] = v;
  }
  __syncthreads();
  int co = threadIdx.x;
  float acc[8];
#pragma unroll
  for (int s = 0; s < 8; ++s) acc[s] = b2[co];
#pragma unroll 2
  for (int pp = 0; pp < 4; ++pp)
    for (int ci = 0; ci < 64; ++ci) {
      float wv = w2[((pp << 6) + ci) * 64 + co];
      float4 i0 = *(const float4*)&inT[pp][ci][0];
      float4 i1 = *(const float4*)&inT[pp][ci][4];
      acc[0] += i0.x * wv; acc[1] += i0.y * wv; acc[2] += i0.z * wv; acc[3] += i0.w * wv;
      acc[4] += i1.x * wv; acc[5] += i1.y * wv; acc[6] += i1.z * wv; acc[7] += i1.w * wv;
    }
  int smax = min(8, n - s0);
  for (int s = 0; s < smax; ++s) {
    float o = g2[co] * acc[s] * BN_INV + be2[co];
    feats[((size_t)(b * CAPM) + s0 + s) * 64 + co] = fmaxf(o, 0.f);
  }
}

// ---------------- QKV projection -> f16 buffers (8 sites/block) --------------

__global__ void k_qkv(const float* __restrict__ feats, const int* __restrict__ list2,
                      const int* __restrict__ cnt,
                      const float* __restrict__ wpe, const float* __restrict__ bpe,
                      const float* __restrict__ wq, const float* __restrict__ bq,
                      const float* __restrict__ wk, const float* __restrict__ bk,
                      const float* __restrict__ wv, const float* __restrict__ bv,
                      int layer, _Float16* __restrict__ qf, _Float16* __restrict__ kf,
                      _Float16* __restrict__ vt) {
  int b = blockIdx.x & 7;
  int sblk = blockIdx.x >> 3;       // 0..255
  int s0 = sblk * 8;
  int n = min(cnt[2 * BDIM + b], CAPM);
  if (s0 >= n) return;
  __shared__ float hT[64][8];
  for (int idx = threadIdx.x; idx < 512; idx += 128) {
    int s = idx & 7, c = idx >> 3;
    float hv = 0.f;
    int sg = s0 + s;
    if (sg < n) {
      int p = list2[b * CAPM + sg];
      int i = p / 125, j = p - i * 125;
      hv = feats[((size_t)(b * CAPM) + sg) * 64 + c]
         + (float)i * (1.f / 125.f) * wpe[(layer * 2 + 0) * 64 + c]
         + (float)j * (1.f / 125.f) * wpe[(layer * 2 + 1) * 64 + c]
         + bpe[layer * 64 + c];
    }
    hT[c][s] = hv;
  }
  __syncthreads();
  int o = threadIdx.x;
  float accq[8], acck[8], accv[8];
  float bqv = bq[layer * 128 + o], bkv = bk[layer * 128 + o], bvv = bv[layer * 128 + o];
#pragma unroll
  for (int s = 0; s < 8; ++s) { accq[s] = bqv; acck[s] = bkv; accv[s] = bvv; }
  const float* wq_ = wq + (size_t)layer * 64 * 128 + o;
  const float* wk_ = wk + (size_t)layer * 64 * 128 + o;
  const float* wv_ = wv + (size_t)layer * 64 * 128 + o;
  for (int c = 0; c < 64; ++c) {
    float wqv = wq_[c * 128], wkv = wk_[c * 128], wvv = wv_[c * 128];
    float4 h0 = *(const float4*)&hT[c][0];
    float4 h1 = *(const float4*)&hT[c][4];
    float hh[8] = {h0.x, h0.y, h0.z, h0.w, h1.x, h1.y, h1.z, h1.w};
#pragma unroll
    for (int s = 0; s < 8; ++s) {
      accq[s] += hh[s] * wqv; acck[s] += hh[s] * wkv; accv[s] += hh[s] * wvv;
    }
  }
  int hd = o >> 5, d = o & 31;
  size_t bh = (size_t)(b * NHEADS + hd);
  int smax = min(8, n - s0);
  for (int s = 0; s < smax; ++s) {
    size_t rb = (bh * CAPM + s0 + s) * 32 + d;
    qf[rb] = (_Float16)accq[s];
    kf[rb] = (_Float16)acck[s];
    vt[(bh * 32 + d) * CAPM + s0 + s] = (_Float16)accv[s];
  }
}

// ---------------- split-K MFMA flash attention -------------------------------
// Wave = (b, h, 16q tile, ks). PV computed as mfma(V, P) so the accumulator
// COLUMN = query qr = this lane's softmax state: rescale is lane-local
// (acc *= f_, no shfl), l is accumulated lane-locally and cross-g summed once
// at the end. Only 2 shfls (max) remain per 64-key tile. Barrier-free, reg
// ping-pong prefetch, image->XCD swizzle. Partials unnormalized + (m,l).

union U4H8 { uint4 u; f16x8 h; };
union PKU  { _Float16 h[2]; unsigned int u; };

#define LOADK(K0, K1, K2, K3, T0)                                          \
  K0 = *(const f16x8*)(kf + (bh + (T0) + qr) * 32 + g8);                   \
  K1 = *(const f16x8*)(kf + (bh + (T0) + 16 + qr) * 32 + g8);              \
  K2 = *(const f16x8*)(kf + (bh + (T0) + 32 + qr) * 32 + g8);              \
  K3 = *(const f16x8*)(kf + (bh + (T0) + 48 + qr) * 32 + g8);

#define LOADV(V0, V1, V2, V3, T0)                                          \
  V0 = *(const f16x8*)(vbase + (size_t)qr * CAPM + (T0) + g8);             \
  V1 = *(const f16x8*)(vbase + (size_t)(16 + qr) * CAPM + (T0) + g8);      \
  V2 = *(const f16x8*)(vbase + (size_t)qr * CAPM + (T0) + 32 + g8);        \
  V3 = *(const f16x8*)(vbase + (size_t)(16 + qr) * CAPM + (T0) + 32 + g8);

#define PROCESS(K0, K1, K2, K3, V0, V1, V2, V3, T0)                        \
  {                                                                        \
    f32x4 z = {0.f, 0.f, 0.f, 0.f};                                        \
    f32x4 st0 = __builtin_amdgcn_mfma_f32_16x16x32_f16(K0, fq, z, 0, 0, 0);\
    f32x4 st1 = __builtin_amdgcn_mfma_f32_16x16x32_f16(K1, fq, z, 0, 0, 0);\
    f32x4 st2 = __builtin_amdgcn_mfma_f32_16x16x32_f16(K2, fq, z, 0, 0, 0);\
    f32x4 st3 = __builtin_amdgcn_mfma_f32_16x16x32_f16(K3, fq, z, 0, 0, 0);\
    if ((T0) + 64 > n) {                                                   \
      _Pragma("unroll") for (int r = 0; r < 4; ++r) {                      \
        if ((T0) + 4 * g + r >= n)      st0[r] = -1e30f;                   \
        if ((T0) + 16 + 4 * g + r >= n) st1[r] = -1e30f;                   \
        if ((T0) + 32 + 4 * g + r >= n) st2[r] = -1e30f;                   \
        if ((T0) + 48 + 4 * g + r >= n) st3[r] = -1e30f;                   \
      }                                                                    \
    }                                                                      \
    float tm = st0[0];                                                     \
    _Pragma("unroll") for (int r = 1; r < 4; ++r) tm = fmaxf(tm, st0[r]);  \
    _Pragma("unroll") for (int r = 0; r < 4; ++r) tm = fmaxf(tm, st1[r]);  \
    _Pragma("unroll") for (int r = 0; r < 4; ++r) tm = fmaxf(tm, st2[r]);  \
    _Pragma("unroll") for (int r = 0; r < 4; ++r) tm = fmaxf(tm, st3[r]);  \
    tm = fmaxf(tm, __shfl_xor(tm, 16));                                    \
    tm = fmaxf(tm, __shfl_xor(tm, 32));                                    \
    float mn = fmaxf(m, tm * ATT_SCALE);                                   \
    float f_ = __expf(m - mn);                                             \
    m = mn;                                                                \
    float ls = 0.f;                                                        \
    {                                                                      \
      PKU a, c;                                                            \
      a.h[0] = (_Float16)__expf(st0[0] * ATT_SCALE - mn);                  \
      a.h[1] = (_Float16)__expf(st0[1] * ATT_SCALE - mn);                  \
      c.h[0] = (_Float16)__expf(st0[2] * ATT_SCALE - mn);                  \
      c.h[1] = (_Float16)__expf(st0[3] * ATT_SCALE - mn);                  \
      ls += (float)a.h[0] + (float)a.h[1] + (float)c.h[0] + (float)c.h[1]; \
      P[(qr * 32 + 0 + 2 * g) ^ swz] = a.u;                                \
      P[(qr * 32 + 1 + 2 * g) ^ swz] = c.u;                                \
      a.h[0] = (_Float16)__expf(st1[0] * ATT_SCALE - mn);                  \
      a.h[1] = (_Float16)__expf(st1[1] * ATT_SCALE - mn);                  \
      c.h[0] = (_Float16)__expf(st1[2] * ATT_SCALE - mn);                  \
      c.h[1] = (_Float16)__expf(st1[3] * ATT_SCALE - mn);                  \
      ls += (float)a.h[0] + (float)a.h[1] + (float)c.h[0] + (float)c.h[1]; \
      P[(qr * 32 + 8 + 2 * g) ^ swz] = a.u;                                \
      P[(qr * 32 + 9 + 2 * g) ^ swz] = c.u;                                \
      a.h[0] = (_Float16)__expf(st2[0] * ATT_SCALE - mn);                  \
      a.h[1] = (_Float16)__expf(st2[1] * ATT_SCALE - mn);                  \
      c.h[0] = (_Float16)__expf(st2[2] * ATT_SCALE - mn);                  \
      c.h[1] = (_Float16)__expf(st2[3] * ATT_SCALE - mn);                  \
      ls += (float)a.h[0] + (float)a.h[1] + (float)c.h[0] + (float)c.h[1]; \
      P[(qr * 32 + 16 + 2 * g) ^ swz] = a.u;                               \
      P[(qr * 32 + 17 + 2 * g) ^ swz] = c.u;                               \
      a.h[0] = (_Float16)__expf(st3[0] * ATT_SCALE - mn);                  \
      a.h[1] = (_Float16)__expf(st3[1] * ATT_SCALE - mn);                  \
      c.h[0] = (_Float16)__expf(st3[2] * ATT_SCALE - mn);                  \
      c.h[1] = (_Float16)__expf(st3[3] * ATT_SCALE - mn);                  \
      ls += (float)a.h[0] + (float)a.h[1] + (float)c.h[0] + (float)c.h[1]; \
      P[(qr * 32 + 24 + 2 * g) ^ swz] = a.u;                               \
      P[(qr * 32 + 25 + 2 * g) ^ swz] = c.u;                               \
    }                                                                      \
    l = l * f_ + ls;                                                       \
    __builtin_amdgcn_sched_barrier(0);                                     \
    U4H8 pa0, pa1;                                                         \
    pa0.u = *(const uint4*)&P[(qr * 32 + 4 * g) ^ swz];                    \
    pa1.u = *(const uint4*)&P[(qr * 32 + 16 + 4 * g) ^ swz];               \
    acc0[0] *= f_; acc0[1] *= f_; acc0[2] *= f_; acc0[3] *= f_;            \
    acc1[0] *= f_; acc1[1] *= f_; acc1[2] *= f_; acc1[3] *= f_;            \
    acc0 = __builtin_amdgcn_mfma_f32_16x16x32_f16(V0, pa0.h, acc0, 0, 0, 0);\
    acc1 = __builtin_amdgcn_mfma_f32_16x16x32_f16(V1, pa0.h, acc1, 0, 0, 0);\
    acc0 = __builtin_amdgcn_mfma_f32_16x16x32_f16(V2, pa1.h, acc0, 0, 0, 0);\
    acc1 = __builtin_amdgcn_mfma_f32_16x16x32_f16(V3, pa1.h, acc1, 0, 0, 0);\
  }

__global__ __launch_bounds__(64, 4) void k_attn(
    const _Float16* __restrict__ qf, const _Float16* __restrict__ kf,
    const _Float16* __restrict__ vt, const int* __restrict__ cnt,
    float* __restrict__ pacc, float* __restrict__ pml) {
  int b  = blockIdx.x & 7;            // image -> XCD
  int rr = blockIdx.x >> 3;
  int qt = rr & 127;
  rr >>= 7;
  int h  = rr & 3;
  int ks = rr >> 2;                   // key chunk 0..3
  int n = min(cnt[2 * BDIM + b], CAPM);
  int q0 = qt * 16;
  if (q0 >= n) return;
  int lane = threadIdx.x;
  int g = lane >> 4, qr = lane & 15;
  int g8 = g * 8;
  size_t bh = (size_t)(b * NHEADS + h) * CAPM;
  const _Float16* vbase = vt + (size_t)(b * NHEADS + h) * 32 * CAPM;
  f16x8 fq = *(const f16x8*)(qf + (bh + q0 + qr) * 32 + g8);   // Q B-frag
  f32x4 acc0 = {0.f, 0.f, 0.f, 0.f}, acc1 = {0.f, 0.f, 0.f, 0.f};
  float m = -1e30f, l = 0.f;
  __shared__ unsigned int P[512];     // 16q x 64k f16, XOR-swizzled (1 wave)
  int swz = (qr & 7) << 2;

  int nt = (n + 63) >> 6;
  int tpc = (nt + KSPLIT - 1) / KSPLIT;
  int tb = ks * tpc, te = min(nt, tb + tpc);
  if (tb < te) {
    f16x8 ka0, ka1, ka2, ka3, va0, va1, va2, va3;
    f16x8 kb0, kb1, kb2, kb3, vb0, vb1, vb2, vb3;
    LOADK(ka0, ka1, ka2, ka3, tb * 64)
    LOADV(va0, va1, va2, va3, tb * 64)
    for (int t = tb; t < te; t += 2) {
      if (t + 1 < te) {
        LOADK(kb0, kb1, kb2, kb3, (t + 1) * 64)
        LOADV(vb0, vb1, vb2, vb3, (t + 1) * 64)
      }
      PROCESS(ka0, ka1, ka2, ka3, va0, va1, va2, va3, t * 64)
      if (t + 1 < te) {
        if (t + 2 < te) {
          LOADK(ka0, ka1, ka2, ka3, (t + 2) * 64)
          LOADV(va0, va1, va2, va3, (t + 2) * 64)
        }
        PROCESS(kb0, kb1, kb2, kb3, vb0, vb1, vb2, vb3, (t + 1) * 64)
      }
    }
  }
  // sum l across the 4 g-groups (lanes qr, qr+16, qr+32, qr+48)
  l += __shfl_xor(l, 16);
  l += __shfl_xor(l, 32);
  // write unnormalized partials + (m,l); lane (g,qr): token q0+qr,
  // channels 4g+r (acc0) and 16+4g+r (acc1)
  int tok = q0 + qr;
  if (tok < n) {
    float* pp = pacc + ((bh + tok) * KSPLIT + ks) * 32;
#pragma unroll
    for (int r = 0; r < 4; ++r) {
      pp[4 * g + r] = acc0[r];
      pp[16 + 4 * g + r] = acc1[r];
    }
    if (g == 0) {
      float* pm = pml + ((bh + tok) * KSPLIT + ks) * 2;
      pm[0] = m; pm[1] = l;
    }
  }
}

// ---------------- combine + output projection + residual ---------------------

__global__ __launch_bounds__(256) void k_cproj(
    const float* __restrict__ pacc, const float* __restrict__ pml,
    const float* __restrict__ wo, const float* __restrict__ bo,
    const int* __restrict__ cnt, int layer, float* __restrict__ feats) {
  int b = blockIdx.x & 7;
  int sblk = blockIdx.x >> 3;        // 0..511
  int s0 = sblk * 4;
  int n = min(cnt[2 * BDIM + b], CAPM);
  if (s0 >= n) return;
  __shared__ float oT[128][4];
  __shared__ float wgt[4][4][4];     // [site][head][chunk]
  __shared__ float invL[4][4];       // [site][head]
  int t = threadIdx.x;
  if (t < 16) {
    int s = t >> 2, h = t & 3;
    const float* pm = pml + (((size_t)(b * NHEADS + h) * CAPM + s0 + s) * KSPLIT) * 2;
    float m0 = pm[0], l0 = pm[1];
    float m1 = pm[2], l1 = pm[3];
    float m2 = pm[4], l2 = pm[5];
    float m3 = pm[6], l3 = pm[7];
    float M = fmaxf(fmaxf(m0, m1), fmaxf(m2, m3));
    float w0_ = __expf(m0 - M), w1_ = __expf(m1 - M);
    float w2_ = __expf(m2 - M), w3_ = __expf(m3 - M);
    float L = w0_ * l0 + w1_ * l1 + w2_ * l2 + w3_ * l3;
    wgt[s][h][0] = w0_; wgt[s][h][1] = w1_;
    wgt[s][h][2] = w2_; wgt[s][h][3] = w3_;
    invL[s][h] = 1.f / L;
  }
  __syncthreads();
#pragma unroll
  for (int k = 0; k < 2; ++k) {
    int id = t + k * 256;            // 512 = 128ch x 4 sites
    int c = id >> 2, s = id & 3;
    int h = c >> 5, d = c & 31;
    const float* pp = pacc + (((size_t)(b * NHEADS + h) * CAPM + s0 + s) * KSPLIT) * 32 + d;
    float v = pp[0]  * wgt[s][h][0] + pp[32] * wgt[s][h][1]
            + pp[64] * wgt[s][h][2] + pp[96] * wgt[s][h][3];
    oT[c][s] = v * invL[s][h];
  }
  __syncthreads();
  int s = t >> 6, co = t & 63;
  float acc = bo[layer * 64 + co];
  const float* w = wo + (size_t)layer * 128 * 64 + co;
#pragma unroll 8
  for (int c = 0; c < 128; ++c) acc += oT[c][s] * w[c * 64];
  int tok = s0 + s;
  if (tok < n) feats[((size_t)(b * CAPM) + tok) * 64 + co] += acc;
}

// ---------------- pooled head (fused 2-stage reduce + GEMV) ------------------

__global__ __launch_bounds__(1024) void k_head(
    const float* __restrict__ feats, const float* __restrict__ wh,
    const float* __restrict__ bhd, const int* __restrict__ cnt,
    float* __restrict__ out) {
  int b = blockIdx.x;
  int n = min(cnt[2 * BDIM + b], CAPM);
  int c = threadIdx.x & 63, chunk = threadIdx.x >> 6;   // 16 chunks
  int lo = chunk * 128, hi = min(n, lo + 128);
  float s = 0.f;
  for (int mm = lo; mm < hi; ++mm)
    s += feats[((size_t)(b * CAPM) + mm) * 64 + c];
  __shared__ float red[16][64];
  __shared__ float pooled[64];
  red[chunk][c] = s;
  __syncthreads();
  if (threadIdx.x < 64) {
    float tot = 0.f;
#pragma unroll
    for (int k = 0; k < 16; ++k) tot += red[k][c];
    pooled[c] = tot / (float)max(n, 1);
  }
  __syncthreads();
  if (threadIdx.x < 4) {
    float o = bhd[threadIdx.x];
#pragma unroll
    for (int c2 = 0; c2 < 64; ++c2) o += pooled[c2] * wh[c2 * 4 + threadIdx.x];
    out[b * 4 + threadIdx.x] = o;
  }
}

// ---------------- launch -----------------------------------------------------

extern "C" void kernel_launch(void* const* d_in, const int* in_sizes, int n_in,
                              void* d_out, int out_size, void* d_ws, size_t ws_size,
                              hipStream_t stream) {
  const float* x   = (const float*)d_in[0];
  const float* w0  = (const float*)d_in[1];
  const float* b0  = (const float*)d_in[2];
  const float* g0  = (const float*)d_in[3];
  const float* be0 = (const float*)d_in[4];
  const float* w1  = (const float*)d_in[5];
  const float* b1  = (const float*)d_in[6];
  const float* g1  = (const float*)d_in[7];
  const float* be1 = (const float*)d_in[8];
  const float* w2  = (const float*)d_in[9];
  const float* b2  = (const float*)d_in[10];
  const float* g2  = (const float*)d_in[11];
  const float* be2 = (const float*)d_in[12];
  const float* wpe = (const float*)d_in[13];
  const float* bpe = (const float*)d_in[14];
  const float* wq  = (const float*)d_in[15];
  const float* bq  = (const float*)d_in[16];
  const float* wk  = (const float*)d_in[17];
  const float* bk  = (const float*)d_in[18];
  const float* wv  = (const float*)d_in[19];
  const float* bv  = (const float*)d_in[20];
  const float* wo  = (const float*)d_in[21];
  const float* bo  = (const float*)d_in[22];
  const float* wh  = (const float*)d_in[23];
  const float* bh  = (const float*)d_in[24];

  int* wsI = (int*)d_ws;
  float* wsF = (float*)d_ws;
  unsigned long long* bm = (unsigned long long*)(wsI + E_BM);
  _Float16* qf = (_Float16*)(wsI + E_QF);
  _Float16* kf = (_Float16*)(wsI + E_KF);
  _Float16* vt = (_Float16*)(wsI + E_VT);

  // Zero slot maps + counters only.
  hipMemsetAsync(d_ws, 0, E_ZEND * 4, stream);

  // level 0
  k_cnt0<<<dim3(NB0, BDIM), 256, 0, stream>>>(x, wsI + E_BC + 0 * BDIM * 1024,
                                              bm + 0 * BDIM * 4096);
  k_scan<<<BDIM, 256, 0, stream>>>(wsI + E_BC + 0 * BDIM * 1024,
                                   wsI + E_BO + 0 * BDIM * 1024,
                                   wsI + E_CNT, NB0, 0);
  k_emit0<<<dim3(NB0, BDIM), 256, 0, stream>>>(bm + 0 * BDIM * 4096,
                                               wsI + E_BO + 0 * BDIM * 1024,
                                               wsI + E_MAP0, wsI + E_LIST0);
  k_y0<<<(BDIM * CAP0 * 32) / 256, 256, 0, stream>>>(
      x, w0, b0, g0, be0, wsI + E_LIST0, wsI + E_CNT, wsF + E_Y0);
  // level 1
  k_cnt1<<<dim3(NB1, BDIM), 256, 0, stream>>>(wsI + E_MAP0,
                                              wsI + E_BC + 1 * BDIM * 1024,
                                              bm + 1 * BDIM * 4096);
  k_scan<<<BDIM, 256, 0, stream>>>(wsI + E_BC + 1 * BDIM * 1024,
                                   wsI + E_BO + 1 * BDIM * 1024,
                                   wsI + E_CNT, NB1, BDIM);
  k_emit1<<<dim3(NB1, BDIM), 256, 0, stream>>>(bm + 1 * BDIM * 4096,
                                               wsI + E_BO + 1 * BDIM * 1024,
                                               wsI + E_MAP1, wsI + E_LIST1);
  k_y1<<<BDIM * (CAP1 / 8), 64, 0, stream>>>(
      wsF + E_Y0, w1, b1, g1, be1, wsI + E_MAP0, wsI + E_LIST1, wsI + E_CNT, wsF + E_Y1);
  // level 2
  k_cnt2<<<dim3(NB2, BDIM), 256, 0, stream>>>(wsI + E_MAP1,
                                              wsI + E_BC + 2 * BDIM * 1024,
                                              bm + 2 * BDIM * 4096);
  k_scan<<<BDIM, 256, 0, stream>>>(wsI + E_BC + 2 * BDIM * 1024,
                                   wsI + E_BO + 2 * BDIM * 1024,
                                   wsI + E_CNT, NB2, 2 * BDIM);
  k_emit2<<<dim3(NB2, BDIM), 256, 0, stream>>>(bm + 2 * BDIM * 4096,
                                               wsI + E_BO + 2 * BDIM * 1024,
                                               wsI + E_LIST2);
  k_y2<<<BDIM * (CAPM / 8), 64, 0, stream>>>(
      wsF + E_Y1, w2, b2, g2, be2, wsI + E_MAP1, wsI + E_LIST2, wsI + E_CNT, wsF + E_FE);

  for (int layer = 0; layer < 2; ++layer) {
    k_qkv<<<BDIM * (CAPM / 8), 128, 0, stream>>>(
        wsF + E_FE, wsI + E_LIST2, wsI + E_CNT, wpe, bpe, wq, bq, wk, bk, wv, bv,
        layer, qf, kf, vt);
    k_attn<<<BDIM * NHEADS * (CAPM / 16) * KSPLIT, 64, 0, stream>>>(
        qf, kf, vt, wsI + E_CNT, wsF + E_PACC, wsF + E_PML);
    k_cproj<<<BDIM * (CAPM / 4), 256, 0, stream>>>(
        wsF + E_PACC, wsF + E_PML, wo, bo, wsI + E_CNT, layer, wsF + E_FE);
  }

  k_head<<<BDIM, 1024, 0, stream>>>(wsF + E_FE, wh, bh, wsI + E_CNT, (float*)d_out);
}

// Round 9
// 246.691 us; speedup vs baseline: 1.0574x; 1.0574x over previous
//
#include <hip/hip_runtime.h>

// Problem constants
#define BDIM   8
#define NPIX   250000   // 500*500
#define G1N    62500    // 250*250
#define G2N    15625    // 125*125
#define NB0    977      // ceil(NPIX/256)
#define NB1    245      // ceil(G1N/256)
#define NB2    62       // ceil(G2N/256)
#define CAP0   4096
#define CAP1   4096
#define CAPM   2048
#define CH     64
#define ACH    128
#define NHEADS 4
#define DH     32
#define KSPLIT 4

static constexpr float BN_INV    = 0.99999500003749969f;   // 1/sqrt(1+1e-5)
static constexpr float ATT_SCALE = 0.17677669529663687f;   // 1/sqrt(32)

typedef _Float16 f16x8 __attribute__((ext_vector_type(8)));
typedef float f32x4 __attribute__((ext_vector_type(4)));

// Workspace word offsets (4-byte units). Zeroed prefix: [0, E_ZEND)
static constexpr size_t E_MAP0  = 0;                                  // int [B*NPIX]
static constexpr size_t E_MAP1  = E_MAP0 + (size_t)BDIM*NPIX;         // int [B*G1N]
static constexpr size_t E_CNT   = E_MAP1 + (size_t)BDIM*G1N;          // int [32]
static constexpr size_t E_ZEND  = E_CNT + 32;
static constexpr size_t E_BC    = E_ZEND;                             // int [3][B][1024]
static constexpr size_t E_BO    = E_BC + (size_t)3*BDIM*1024;         // int [3][B][1024]
static constexpr size_t E_BM    = E_BO + (size_t)3*BDIM*1024;        // ull [3][B][1024][4]
static constexpr size_t E_LIST0 = E_BM + (size_t)3*BDIM*1024*8;      // int [B*CAP0]
static constexpr size_t E_LIST1 = E_LIST0 + (size_t)BDIM*CAP0;
static constexpr size_t E_LIST2 = E_LIST1 + (size_t)BDIM*CAP1;
static constexpr size_t E_Y0    = E_LIST2 + (size_t)BDIM*CAPM;        // f32 [B*CAP0*32]
static constexpr size_t E_Y1    = E_Y0 + (size_t)BDIM*CAP0*32;       // f32 [B*CAP1*64]
static constexpr size_t E_FE    = E_Y1 + (size_t)BDIM*CAP1*64;       // f32 [B*CAPM*64]
static constexpr size_t E_QF    = E_FE + (size_t)BDIM*CAPM*64;       // f16 [32bh][CAPM][32]
static constexpr size_t E_KF    = E_QF + (size_t)32*CAPM*32/2;
static constexpr size_t E_VT    = E_KF + (size_t)32*CAPM*32/2;       // f16 [32bh][32][CAPM]
static constexpr size_t E_O     = E_VT + (size_t)32*CAPM*32/2;       // f16 [B][CAPM][ACH]

// ---------------- deterministic compaction: count / scan / emit --------------

__device__ __forceinline__ bool act0(const float* x, int pix, int b) {
  return (pix < NPIX) && (x[(size_t)b * NPIX + pix] != 0.f);
}
__device__ __forceinline__ bool act1(const int* map0, int p, int b) {
  if (p >= G1N) return false;
  int i = p / 250, j = p - i * 250;
  const int* m = map0 + (size_t)b * NPIX + (2 * i) * 500 + 2 * j;
  return (m[0] | m[1] | m[500] | m[501]) != 0;
}
__device__ __forceinline__ bool act2(const int* map1, int p, int b) {
  if (p >= G2N) return false;
  int i = p / 125, j = p - i * 125;
  const int* m = map1 + (size_t)b * G1N + (2 * i) * 250 + 2 * j;
  return (m[0] | m[1] | m[250] | m[251]) != 0;
}

#define COUNT_BODY(ACT_EXPR)                                            \
  int idx = blockIdx.x * 256 + threadIdx.x;                             \
  int b = blockIdx.y;                                                   \
  bool act = (ACT_EXPR);                                                \
  unsigned long long mask = __ballot(act);                              \
  __shared__ int wc[4];                                                 \
  if ((threadIdx.x & 63) == 0) {                                        \
    wc[threadIdx.x >> 6] = __popcll(mask);                              \
    bm[((size_t)b * 1024 + blockIdx.x) * 4 + (threadIdx.x >> 6)] = mask;\
  }                                                                     \
  __syncthreads();                                                      \
  if (threadIdx.x == 0)                                                 \
    bcnt[b * 1024 + blockIdx.x] = wc[0] + wc[1] + wc[2] + wc[3];

__global__ void k_cnt0(const float* __restrict__ x, int* __restrict__ bcnt,
                       unsigned long long* __restrict__ bm) {
  COUNT_BODY(act0(x, idx, b))
}
__global__ void k_cnt1(const int* __restrict__ map0, int* __restrict__ bcnt,
                       unsigned long long* __restrict__ bm) {
  COUNT_BODY(act1(map0, idx, b))
}
__global__ void k_cnt2(const int* __restrict__ map1, int* __restrict__ bcnt,
                       unsigned long long* __restrict__ bm) {
  COUNT_BODY(act2(map1, idx, b))
}

// one block/image, 256 threads, shfl scan (1 barrier). nblk <= 1024.
__global__ __launch_bounds__(256) void k_scan(const int* __restrict__ bcnt,
                                              int* __restrict__ boff,
                                              int* __restrict__ cnt,
                                              int nblk, int cbase) {
  int b = blockIdx.x;
  int t = threadIdx.x;
  int base = t * 4;
  int v[4];
  int ts = 0;
#pragma unroll
  for (int u = 0; u < 4; ++u) {
    v[u] = (base + u < nblk) ? bcnt[b * 1024 + base + u] : 0;
    ts += v[u];
  }
  int lane = t & 63, w = t >> 6;
  int incl = ts;
#pragma unroll
  for (int off = 1; off < 64; off <<= 1) {
    int o = __shfl_up(incl, off, 64);
    if (lane >= off) incl += o;
  }
  __shared__ int wsum[4];
  if (lane == 63) wsum[w] = incl;
  __syncthreads();
  int woff = 0;
#pragma unroll
  for (int k = 0; k < 3; ++k) if (k < w) woff += wsum[k];
  int run = woff + incl - ts;
#pragma unroll
  for (int u = 0; u < 4; ++u) {
    if (base + u < nblk) boff[b * 1024 + base + u] = run;
    run += v[u];
  }
  if (t == 255) cnt[cbase + b] = run;
}

// emit: replay stored ballot masks (no recompute / no re-read of inputs)
#define EMIT_PROLOG                                                     \
  int idx = blockIdx.x * 256 + threadIdx.x;                             \
  int b = blockIdx.y;                                                   \
  int lane = threadIdx.x & 63;                                          \
  unsigned long long mask =                                             \
      bm[((size_t)b * 1024 + blockIdx.x) * 4 + (threadIdx.x >> 6)];     \
  bool act = (mask >> lane) & 1;                                        \
  __shared__ int wbase[4];                                              \
  if (lane == 0) wbase[threadIdx.x >> 6] = __popcll(mask);              \
  __syncthreads();                                                      \
  if (threadIdx.x == 0) {                                               \
    int s = boff[b * 1024 + blockIdx.x];                                \
    for (int w = 0; w < 4; ++w) { int c = wbase[w]; wbase[w] = s; s += c; } \
  }                                                                     \
  __syncthreads();                                                      \
  int slot = wbase[threadIdx.x >> 6] + __popcll(mask & ((1ull << lane) - 1ull));

__global__ void k_emit0(const unsigned long long* __restrict__ bm,
                        const int* __restrict__ boff,
                        int* __restrict__ map0, int* __restrict__ list0) {
  EMIT_PROLOG
  if (act && slot < CAP0) {
    list0[b * CAP0 + slot] = idx;
    map0[(size_t)b * NPIX + idx] = slot + 1;
  }
}
__global__ void k_emit1(const unsigned long long* __restrict__ bm,
                        const int* __restrict__ boff,
                        int* __restrict__ map1, int* __restrict__ list1) {
  EMIT_PROLOG
  if (act && slot < CAP1) {
    list1[b * CAP1 + slot] = idx;
    map1[(size_t)b * G1N + idx] = slot + 1;
  }
}
__global__ void k_emit2(const unsigned long long* __restrict__ bm,
                        const int* __restrict__ boff,
                        int* __restrict__ list2) {
  EMIT_PROLOG
  if (act && slot < CAPM) list2[b * CAPM + slot] = idx;
}

// ---------------- sparse convs -----------------------------------------------

__global__ void k_y0(const float* __restrict__ x, const float* __restrict__ w0,
                     const float* __restrict__ b0, const float* __restrict__ g0,
                     const float* __restrict__ be0,
                     const int* __restrict__ list0, const int* __restrict__ cnt,
                     float* __restrict__ y0) {
  int t = blockIdx.x * 256 + threadIdx.x;
  int b = t >> 17;
  int r = t & 131071;
  int slot = r >> 5, c = r & 31;
  int n = min(cnt[b], CAP0);
  if (slot >= n) return;
  int pix = list0[b * CAP0 + slot];
  int i = pix / 500, j = pix - i * 500;
  float acc = b0[c];
#pragma unroll
  for (int di = 0; di < 3; ++di) {
    int ii = i + di - 1;
    if ((unsigned)ii >= 500u) continue;
#pragma unroll
    for (int dj = 0; dj < 3; ++dj) {
      int jj = j + dj - 1;
      if ((unsigned)jj >= 500u) continue;
      acc += x[(size_t)b * NPIX + ii * 500 + jj] * w0[(di * 3 + dj) * 32 + c];
    }
  }
  float o = g0[c] * acc * BN_INV + be0[c];
  y0[((size_t)(b * CAP0) + slot) * 32 + c] = fmaxf(o, 0.f);
}

// 256 threads = 4 sub-blocks x 8 sites (32 sites/block)
__global__ __launch_bounds__(256) void k_y1(
    const float* __restrict__ y0, const float* __restrict__ w1,
    const float* __restrict__ b1, const float* __restrict__ g1,
    const float* __restrict__ be1,
    const int* __restrict__ map0, const int* __restrict__ list1,
    const int* __restrict__ cnt, float* __restrict__ y1) {
  int b = blockIdx.x & 7;
  int qblk = blockIdx.x >> 3;       // 0..127
  int sub = threadIdx.x >> 6;
  int co = threadIdx.x & 63;
  int n = min(cnt[BDIM + b], CAP1);
  if (qblk * 32 >= n) return;       // block-uniform
  int s0 = qblk * 32 + sub * 8;
  __shared__ float inT[4][4][32][8];
  for (int idx = co; idx < 1024; idx += 64) {
    int s = idx & 7;
    int r = idx >> 3;
    int ci = r & 31, pp = r >> 5;
    float v = 0.f;
    int sg = s0 + s;
    if (sg < n) {
      int p = list1[b * CAP1 + sg];
      int i = p / 250, j = p - i * 250;
      int sm = map0[(size_t)b * NPIX + (2 * i + (pp >> 1)) * 500 + (2 * j + (pp & 1))];
      if (sm) v = y0[((size_t)(b * CAP0) + (sm - 1)) * 32 + ci];
    }
    inT[sub][pp][ci][s] = v;
  }
  __syncthreads();
  float acc[8];
#pragma unroll
  for (int s = 0; s < 8; ++s) acc[s] = b1[co];
#pragma unroll 2
  for (int pp = 0; pp < 4; ++pp)
    for (int ci = 0; ci < 32; ++ci) {
      float wv = w1[((pp << 5) + ci) * 64 + co];
      float4 i0 = *(const float4*)&inT[sub][pp][ci][0];
      float4 i1 = *(const float4*)&inT[sub][pp][ci][4];
      acc[0] += i0.x * wv; acc[1] += i0.y * wv; acc[2] += i0.z * wv; acc[3] += i0.w * wv;
      acc[4] += i1.x * wv; acc[5] += i1.y * wv; acc[6] += i1.z * wv; acc[7] += i1.w * wv;
    }
  int smax = min(8, n - s0);
  for (int s = 0; s < smax; ++s) {
    float o = g1[co] * acc[s] * BN_INV + be1[co];
    y1[((size_t)(b * CAP1) + s0 + s) * 64 + co] = fmaxf(o, 0.f);
  }
}

// 256 threads = 4 sub-blocks x 8 sites (32 sites/block)
__global__ __launch_bounds__(256) void k_y2(
    const float* __restrict__ y1, const float* __restrict__ w2,
    const float* __restrict__ b2, const float* __restrict__ g2,
    const float* __restrict__ be2,
    const int* __restrict__ map1, const int* __restrict__ list2,
    const int* __restrict__ cnt, float* __restrict__ feats) {
  int b = blockIdx.x & 7;
  int qblk = blockIdx.x >> 3;       // 0..63
  int sub = threadIdx.x >> 6;
  int co = threadIdx.x & 63;
  int n = min(cnt[2 * BDIM + b], CAPM);
  if (qblk * 32 >= n) return;
  int s0 = qblk * 32 + sub * 8;
  __shared__ float inT[4][4][64][8];   // 32KB
  for (int idx = co; idx < 2048; idx += 64) {
    int s = idx & 7;
    int r = idx >> 3;
    int ci = r & 63, pp = r >> 6;
    float v = 0.f;
    int sg = s0 + s;
    if (sg < n) {
      int p = list2[b * CAPM + sg];
      int i = p / 125, j = p - i * 125;
      int sm = map1[(size_t)b * G1N + (2 * i + (pp >> 1)) * 250 + (2 * j + (pp & 1))];
      if (sm) v = y1[((size_t)(b * CAP1) + (sm - 1)) * 64 + ci];
    }
    inT[sub][pp][ci][s] = v;
  }
  __syncthreads();
  float acc[8];
#pragma unroll
  for (int s = 0; s < 8; ++s) acc[s] = b2[co];
#pragma unroll 2
  for (int pp = 0; pp < 4; ++pp)
    for (int ci = 0; ci < 64; ++ci) {
      float wv = w2[((pp << 6) + ci) * 64 + co];
      float4 i0 = *(const float4*)&inT[sub][pp][ci][0];
      float4 i1 = *(const float4*)&inT[sub][pp][ci][4];
      acc[0] += i0.x * wv; acc[1] += i0.y * wv; acc[2] += i0.z * wv; acc[3] += i0.w * wv;
      acc[4] += i1.x * wv; acc[5] += i1.y * wv; acc[6] += i1.z * wv; acc[7] += i1.w * wv;
    }
  int smax = min(8, n - s0);
  for (int s = 0; s < smax; ++s) {
    float o = g2[co] * acc[s] * BN_INV + be2[co];
    feats[((size_t)(b * CAPM) + s0 + s) * 64 + co] = fmaxf(o, 0.f);
  }
}

// ---------------- QKV projection (256 thr = 2 subs x 8 sites) ----------------

__global__ __launch_bounds__(256) void k_qkv(
    const float* __restrict__ feats, const int* __restrict__ list2,
    const int* __restrict__ cnt,
    const float* __restrict__ wpe, const float* __restrict__ bpe,
    const float* __restrict__ wq, const float* __restrict__ bq,
    const float* __restrict__ wk, const float* __restrict__ bk,
    const float* __restrict__ wv, const float* __restrict__ bv,
    int layer, _Float16* __restrict__ qf, _Float16* __restrict__ kf,
    _Float16* __restrict__ vt) {
  int b = blockIdx.x & 7;
  int qblk = blockIdx.x >> 3;       // 0..127 (16 sites each)
  int sub = threadIdx.x >> 7;
  int o = threadIdx.x & 127;
  int n = min(cnt[2 * BDIM + b], CAPM);
  if (qblk * 16 >= n) return;
  int s0 = qblk * 16 + sub * 8;
  __shared__ float hT[2][64][8];
  for (int idx = o; idx < 512; idx += 128) {
    int s = idx & 7, c = idx >> 3;
    float hv = 0.f;
    int sg = s0 + s;
    if (sg < n) {
      int p = list2[b * CAPM + sg];
      int i = p / 125, j = p - i * 125;
      hv = feats[((size_t)(b * CAPM) + sg) * 64 + c]
         + (float)i * (1.f / 125.f) * wpe[(layer * 2 + 0) * 64 + c]
         + (float)j * (1.f / 125.f) * wpe[(layer * 2 + 1) * 64 + c]
         + bpe[layer * 64 + c];
    }
    hT[sub][c][s] = hv;
  }
  __syncthreads();
  float accq[8], acck[8], accv[8];
  float bqv = bq[layer * 128 + o], bkv = bk[layer * 128 + o], bvv = bv[layer * 128 + o];
#pragma unroll
  for (int s = 0; s < 8; ++s) { accq[s] = bqv; acck[s] = bkv; accv[s] = bvv; }
  const float* wq_ = wq + (size_t)layer * 64 * 128 + o;
  const float* wk_ = wk + (size_t)layer * 64 * 128 + o;
  const float* wv_ = wv + (size_t)layer * 64 * 128 + o;
  for (int c = 0; c < 64; ++c) {
    float wqv = wq_[c * 128], wkv = wk_[c * 128], wvv = wv_[c * 128];
    float4 h0 = *(const float4*)&hT[sub][c][0];
    float4 h1 = *(const float4*)&hT[sub][c][4];
    float hh[8] = {h0.x, h0.y, h0.z, h0.w, h1.x, h1.y, h1.z, h1.w};
#pragma unroll
    for (int s = 0; s < 8; ++s) {
      accq[s] += hh[s] * wqv; acck[s] += hh[s] * wkv; accv[s] += hh[s] * wvv;
    }
  }
  int hd = o >> 5, d = o & 31;
  size_t bh = (size_t)(b * NHEADS + hd);
  int smax = min(8, n - s0);
  for (int s = 0; s < smax; ++s) {
    size_t rb = (bh * CAPM + s0 + s) * 32 + d;
    qf[rb] = (_Float16)accq[s];
    kf[rb] = (_Float16)acck[s];
    vt[(bh * 32 + d) * CAPM + s0 + s] = (_Float16)accv[s];
  }
}

// ---------------- split-K MFMA flash attention (4 waves = 4 K-chunks) --------
// Block = (b, h, 16q tile); wave ks handles key-chunk ks. Flash loop is
// barrier-free (wave-private P). One __syncthreads at the end; combine of the
// 4 partials in LDS; normalized f16 output written directly (no global
// partials). PV as mfma(V, P): acc column = lane's own query -> lane-local
// rescale. Image->XCD grid swizzle.

union U4H8 { uint4 u; f16x8 h; };
union PKU  { _Float16 h[2]; unsigned int u; };

#define LOADK(K0, K1, K2, K3, T0)                                          \
  K0 = *(const f16x8*)(kf + (bh + (T0) + qr) * 32 + g8);                   \
  K1 = *(const f16x8*)(kf + (bh + (T0) + 16 + qr) * 32 + g8);              \
  K2 = *(const f16x8*)(kf + (bh + (T0) + 32 + qr) * 32 + g8);              \
  K3 = *(const f16x8*)(kf + (bh + (T0) + 48 + qr) * 32 + g8);

#define LOADV(V0, V1, V2, V3, T0)                                          \
  V0 = *(const f16x8*)(vbase + (size_t)qr * CAPM + (T0) + g8);             \
  V1 = *(const f16x8*)(vbase + (size_t)(16 + qr) * CAPM + (T0) + g8);      \
  V2 = *(const f16x8*)(vbase + (size_t)qr * CAPM + (T0) + 32 + g8);        \
  V3 = *(const f16x8*)(vbase + (size_t)(16 + qr) * CAPM + (T0) + 32 + g8);

#define PROCESS(K0, K1, K2, K3, V0, V1, V2, V3, T0)                        \
  {                                                                        \
    f32x4 z = {0.f, 0.f, 0.f, 0.f};                                        \
    f32x4 st0 = __builtin_amdgcn_mfma_f32_16x16x32_f16(K0, fq, z, 0, 0, 0);\
    f32x4 st1 = __builtin_amdgcn_mfma_f32_16x16x32_f16(K1, fq, z, 0, 0, 0);\
    f32x4 st2 = __builtin_amdgcn_mfma_f32_16x16x32_f16(K2, fq, z, 0, 0, 0);\
    f32x4 st3 = __builtin_amdgcn_mfma_f32_16x16x32_f16(K3, fq, z, 0, 0, 0);\
    if ((T0) + 64 > n) {                                                   \
      _Pragma("unroll") for (int r = 0; r < 4; ++r) {                      \
        if ((T0) + 4 * g + r >= n)      st0[r] = -1e30f;                   \
        if ((T0) + 16 + 4 * g + r >= n) st1[r] = -1e30f;                   \
        if ((T0) + 32 + 4 * g + r >= n) st2[r] = -1e30f;                   \
        if ((T0) + 48 + 4 * g + r >= n) st3[r] = -1e30f;                   \
      }                                                                    \
    }                                                                      \
    float tm = st0[0];                                                     \
    _Pragma("unroll") for (int r = 1; r < 4; ++r) tm = fmaxf(tm, st0[r]);  \
    _Pragma("unroll") for (int r = 0; r < 4; ++r) tm = fmaxf(tm, st1[r]);  \
    _Pragma("unroll") for (int r = 0; r < 4; ++r) tm = fmaxf(tm, st2[r]);  \
    _Pragma("unroll") for (int r = 0; r < 4; ++r) tm = fmaxf(tm, st3[r]);  \
    tm = fmaxf(tm, __shfl_xor(tm, 16));                                    \
    tm = fmaxf(tm, __shfl_xor(tm, 32));                                    \
    float mn = fmaxf(m, tm * ATT_SCALE);                                   \
    float f_ = __expf(m - mn);                                             \
    m = mn;                                                                \
    float ls = 0.f;                                                        \
    {                                                                      \
      PKU a, c;                                                            \
      a.h[0] = (_Float16)__expf(st0[0] * ATT_SCALE - mn);                  \
      a.h[1] = (_Float16)__expf(st0[1] * ATT_SCALE - mn);                  \
      c.h[0] = (_Float16)__expf(st0[2] * ATT_SCALE - mn);                  \
      c.h[1] = (_Float16)__expf(st0[3] * ATT_SCALE - mn);                  \
      ls += (float)a.h[0] + (float)a.h[1] + (float)c.h[0] + (float)c.h[1]; \
      P[(qr * 32 + 0 + 2 * g) ^ swz] = a.u;                                \
      P[(qr * 32 + 1 + 2 * g) ^ swz] = c.u;                                \
      a.h[0] = (_Float16)__expf(st1[0] * ATT_SCALE - mn);                  \
      a.h[1] = (_Float16)__expf(st1[1] * ATT_SCALE - mn);                  \
      c.h[0] = (_Float16)__expf(st1[2] * ATT_SCALE - mn);                  \
      c.h[1] = (_Float16)__expf(st1[3] * ATT_SCALE - mn);                  \
      ls += (float)a.h[0] + (float)a.h[1] + (float)c.h[0] + (float)c.h[1]; \
      P[(qr * 32 + 8 + 2 * g) ^ swz] = a.u;                                \
      P[(qr * 32 + 9 + 2 * g) ^ swz] = c.u;                                \
      a.h[0] = (_Float16)__expf(st2[0] * ATT_SCALE - mn);                  \
      a.h[1] = (_Float16)__expf(st2[1] * ATT_SCALE - mn);                  \
      c.h[0] = (_Float16)__expf(st2[2] * ATT_SCALE - mn);                  \
      c.h[1] = (_Float16)__expf(st2[3] * ATT_SCALE - mn);                  \
      ls += (float)a.h[0] + (float)a.h[1] + (float)c.h[0] + (float)c.h[1]; \
      P[(qr * 32 + 16 + 2 * g) ^ swz] = a.u;                               \
      P[(qr * 32 + 17 + 2 * g) ^ swz] = c.u;                               \
      a.h[0] = (_Float16)__expf(st3[0] * ATT_SCALE - mn);                  \
      a.h[1] = (_Float16)__expf(st3[1] * ATT_SCALE - mn);                  \
      c.h[0] = (_Float16)__expf(st3[2] * ATT_SCALE - mn);                  \
      c.h[1] = (_Float16)__expf(st3[3] * ATT_SCALE - mn);                  \
      ls += (float)a.h[0] + (float)a.h[1] + (float)c.h[0] + (float)c.h[1]; \
      P[(qr * 32 + 24 + 2 * g) ^ swz] = a.u;                               \
      P[(qr * 32 + 25 + 2 * g) ^ swz] = c.u;                               \
    }                                                                      \
    l = l * f_ + ls;                                                       \
    __builtin_amdgcn_sched_barrier(0);                                     \
    U4H8 pa0, pa1;                                                         \
    pa0.u = *(const uint4*)&P[(qr * 32 + 4 * g) ^ swz];                    \
    pa1.u = *(const uint4*)&P[(qr * 32 + 16 + 4 * g) ^ swz];               \
    acc0[0] *= f_; acc0[1] *= f_; acc0[2] *= f_; acc0[3] *= f_;            \
    acc1[0] *= f_; acc1[1] *= f_; acc1[2] *= f_; acc1[3] *= f_;            \
    acc0 = __builtin_amdgcn_mfma_f32_16x16x32_f16(V0, pa0.h, acc0, 0, 0, 0);\
    acc1 = __builtin_amdgcn_mfma_f32_16x16x32_f16(V1, pa0.h, acc1, 0, 0, 0);\
    acc0 = __builtin_amdgcn_mfma_f32_16x16x32_f16(V2, pa1.h, acc0, 0, 0, 0);\
    acc1 = __builtin_amdgcn_mfma_f32_16x16x32_f16(V3, pa1.h, acc1, 0, 0, 0);\
  }

__global__ __launch_bounds__(256) void k_attn(
    const _Float16* __restrict__ qf, const _Float16* __restrict__ kf,
    const _Float16* __restrict__ vt, const int* __restrict__ cnt,
    _Float16* __restrict__ obuf) {
  int b  = blockIdx.x & 7;            // image -> XCD
  int rr = blockIdx.x >> 3;
  int qt = rr & 127;
  int h  = rr >> 7;                   // 0..3
  int n = min(cnt[2 * BDIM + b], CAPM);
  int q0 = qt * 16;
  if (q0 >= n) return;               // block-uniform
  int ks = threadIdx.x >> 6;          // wave = key chunk
  int lane = threadIdx.x & 63;
  int g = lane >> 4, qr = lane & 15;
  int g8 = g * 8;
  size_t bh = (size_t)(b * NHEADS + h) * CAPM;
  const _Float16* vbase = vt + (size_t)(b * NHEADS + h) * 32 * CAPM;
  f16x8 fq = *(const f16x8*)(qf + (bh + q0 + qr) * 32 + g8);   // Q B-frag
  f32x4 acc0 = {0.f, 0.f, 0.f, 0.f}, acc1 = {0.f, 0.f, 0.f, 0.f};
  float m = -1e30f, l = 0.f;
  __shared__ unsigned int P4[4][512];
  __shared__ float partA[4][16][33];   // [chunk][token][ch], padded
  __shared__ float mlA[4][16][2];
  unsigned int* P = P4[ks];
  int swz = (qr & 7) << 2;

  int nt = (n + 63) >> 6;
  int tpc = (nt + KSPLIT - 1) / KSPLIT;
  int tb = ks * tpc, te = min(nt, tb + tpc);
  if (tb < te) {
    f16x8 ka0, ka1, ka2, ka3, va0, va1, va2, va3;
    f16x8 kb0, kb1, kb2, kb3, vb0, vb1, vb2, vb3;
    LOADK(ka0, ka1, ka2, ka3, tb * 64)
    LOADV(va0, va1, va2, va3, tb * 64)
    for (int t = tb; t < te; t += 2) {
      if (t + 1 < te) {
        LOADK(kb0, kb1, kb2, kb3, (t + 1) * 64)
        LOADV(vb0, vb1, vb2, vb3, (t + 1) * 64)
      }
      PROCESS(ka0, ka1, ka2, ka3, va0, va1, va2, va3, t * 64)
      if (t + 1 < te) {
        if (t + 2 < te) {
          LOADK(ka0, ka1, ka2, ka3, (t + 2) * 64)
          LOADV(va0, va1, va2, va3, (t + 2) * 64)
        }
        PROCESS(kb0, kb1, kb2, kb3, vb0, vb1, vb2, vb3, (t + 1) * 64)
      }
    }
  }
  // finalize this chunk: full l per query qr (sum over 4 g-groups)
  l += __shfl_xor(l, 16);
  l += __shfl_xor(l, 32);
  // stash partials in LDS
#pragma unroll
  for (int r = 0; r < 4; ++r) {
    partA[ks][qr][4 * g + r] = acc0[r];
    partA[ks][qr][16 + 4 * g + r] = acc1[r];
  }
  if (g == 0) { mlA[ks][qr][0] = m; mlA[ks][qr][1] = l; }
  __syncthreads();
  // combine: thread t -> token s = t>>4, channels 2(t&15), 2(t&15)+1
  int t = threadIdx.x;
  int s = t >> 4;
  int c0 = (t & 15) * 2;
  int tok = q0 + s;
  if (tok < n) {
    float m0 = mlA[0][s][0], l0 = mlA[0][s][1];
    float m1 = mlA[1][s][0], l1 = mlA[1][s][1];
    float m2 = mlA[2][s][0], l2 = mlA[2][s][1];
    float m3 = mlA[3][s][0], l3 = mlA[3][s][1];
    float M = fmaxf(fmaxf(m0, m1), fmaxf(m2, m3));
    float w0_ = __expf(m0 - M), w1_ = __expf(m1 - M);
    float w2_ = __expf(m2 - M), w3_ = __expf(m3 - M);
    float invL = 1.f / (w0_ * l0 + w1_ * l1 + w2_ * l2 + w3_ * l3);
    float v0 = (partA[0][s][c0] * w0_ + partA[1][s][c0] * w1_ +
                partA[2][s][c0] * w2_ + partA[3][s][c0] * w3_) * invL;
    float v1 = (partA[0][s][c0 + 1] * w0_ + partA[1][s][c0 + 1] * w1_ +
                partA[2][s][c0 + 1] * w2_ + partA[3][s][c0 + 1] * w3_) * invL;
    _Float16* op = obuf + ((size_t)b * CAPM + tok) * ACH + h * DH;
    op[c0] = (_Float16)v0;
    op[c0 + 1] = (_Float16)v1;
  }
}

// ---------------- output projection + residual (4 sites, 256 thr) ------------

__global__ __launch_bounds__(256) void k_proj(
    const _Float16* __restrict__ obuf, const float* __restrict__ wo,
    const float* __restrict__ bo, const int* __restrict__ cnt,
    int layer, float* __restrict__ feats) {
  int b = blockIdx.x & 7;
  int sblk = blockIdx.x >> 3;        // 0..511
  int s0 = sblk * 4;
  int n = min(cnt[2 * BDIM + b], CAPM);
  if (s0 >= n) return;
  __shared__ float oT[128][4];
  int t = threadIdx.x;
#pragma unroll
  for (int k = 0; k < 2; ++k) {
    int id = t + k * 256;            // 512 = 128ch x 4 sites
    int c = id >> 2, s = id & 3;
    int sg = s0 + s;
    oT[c][s] = (sg < n) ? (float)obuf[((size_t)b * CAPM + sg) * ACH + c] : 0.f;
  }
  __syncthreads();
  int s = t >> 6, co = t & 63;
  float acc = bo[layer * 64 + co];
  const float* w = wo + (size_t)layer * 128 * 64 + co;
#pragma unroll 8
  for (int c = 0; c < 128; ++c) acc += oT[c][s] * w[c * 64];
  int tok = s0 + s;
  if (tok < n) feats[((size_t)(b * CAPM) + tok) * 64 + co] += acc;
}

// ---------------- pooled head (fused 2-stage reduce + GEMV) ------------------

__global__ __launch_bounds__(1024) void k_head(
    const float* __restrict__ feats, const float* __restrict__ wh,
    const float* __restrict__ bhd, const int* __restrict__ cnt,
    float* __restrict__ out) {
  int b = blockIdx.x;
  int n = min(cnt[2 * BDIM + b], CAPM);
  int c = threadIdx.x & 63, chunk = threadIdx.x >> 6;   // 16 chunks
  int lo = chunk * 128, hi = min(n, lo + 128);
  float s = 0.f;
  for (int mm = lo; mm < hi; ++mm)
    s += feats[((size_t)(b * CAPM) + mm) * 64 + c];
  __shared__ float red[16][64];
  __shared__ float pooled[64];
  red[chunk][c] = s;
  __syncthreads();
  if (threadIdx.x < 64) {
    float tot = 0.f;
#pragma unroll
    for (int k = 0; k < 16; ++k) tot += red[k][c];
    pooled[c] = tot / (float)max(n, 1);
  }
  __syncthreads();
  if (threadIdx.x < 4) {
    float o = bhd[threadIdx.x];
#pragma unroll
    for (int c2 = 0; c2 < 64; ++c2) o += pooled[c2] * wh[c2 * 4 + threadIdx.x];
    out[b * 4 + threadIdx.x] = o;
  }
}

// ---------------- launch -----------------------------------------------------

extern "C" void kernel_launch(void* const* d_in, const int* in_sizes, int n_in,
                              void* d_out, int out_size, void* d_ws, size_t ws_size,
                              hipStream_t stream) {
  const float* x   = (const float*)d_in[0];
  const float* w0  = (const float*)d_in[1];
  const float* b0  = (const float*)d_in[2];
  const float* g0  = (const float*)d_in[3];
  const float* be0 = (const float*)d_in[4];
  const float* w1  = (const float*)d_in[5];
  const float* b1  = (const float*)d_in[6];
  const float* g1  = (const float*)d_in[7];
  const float* be1 = (const float*)d_in[8];
  const float* w2  = (const float*)d_in[9];
  const float* b2  = (const float*)d_in[10];
  const float* g2  = (const float*)d_in[11];
  const float* be2 = (const float*)d_in[12];
  const float* wpe = (const float*)d_in[13];
  const float* bpe = (const float*)d_in[14];
  const float* wq  = (const float*)d_in[15];
  const float* bq  = (const float*)d_in[16];
  const float* wk  = (const float*)d_in[17];
  const float* bk  = (const float*)d_in[18];
  const float* wv  = (const float*)d_in[19];
  const float* bv  = (const float*)d_in[20];
  const float* wo  = (const float*)d_in[21];
  const float* bo  = (const float*)d_in[22];
  const float* wh  = (const float*)d_in[23];
  const float* bh  = (const float*)d_in[24];

  int* wsI = (int*)d_ws;
  float* wsF = (float*)d_ws;
  unsigned long long* bm = (unsigned long long*)(wsI + E_BM);
  _Float16* qf = (_Float16*)(wsI + E_QF);
  _Float16* kf = (_Float16*)(wsI + E_KF);
  _Float16* vt = (_Float16*)(wsI + E_VT);
  _Float16* ob = (_Float16*)(wsI + E_O);

  // Zero slot maps + counters only.
  hipMemsetAsync(d_ws, 0, E_ZEND * 4, stream);

  // level 0
  k_cnt0<<<dim3(NB0, BDIM), 256, 0, stream>>>(x, wsI + E_BC + 0 * BDIM * 1024,
                                              bm + 0 * BDIM * 4096);
  k_scan<<<BDIM, 256, 0, stream>>>(wsI + E_BC + 0 * BDIM * 1024,
                                   wsI + E_BO + 0 * BDIM * 1024,
                                   wsI + E_CNT, NB0, 0);
  k_emit0<<<dim3(NB0, BDIM), 256, 0, stream>>>(bm + 0 * BDIM * 4096,
                                               wsI + E_BO + 0 * BDIM * 1024,
                                               wsI + E_MAP0, wsI + E_LIST0);
  k_y0<<<(BDIM * CAP0 * 32) / 256, 256, 0, stream>>>(
      x, w0, b0, g0, be0, wsI + E_LIST0, wsI + E_CNT, wsF + E_Y0);
  // level 1
  k_cnt1<<<dim3(NB1, BDIM), 256, 0, stream>>>(wsI + E_MAP0,
                                              wsI + E_BC + 1 * BDIM * 1024,
                                              bm + 1 * BDIM * 4096);
  k_scan<<<BDIM, 256, 0, stream>>>(wsI + E_BC + 1 * BDIM * 1024,
                                   wsI + E_BO + 1 * BDIM * 1024,
                                   wsI + E_CNT, NB1, BDIM);
  k_emit1<<<dim3(NB1, BDIM), 256, 0, stream>>>(bm + 1 * BDIM * 4096,
                                               wsI + E_BO + 1 * BDIM * 1024,
                                               wsI + E_MAP1, wsI + E_LIST1);
  k_y1<<<BDIM * (CAP1 / 32), 256, 0, stream>>>(
      wsF + E_Y0, w1, b1, g1, be1, wsI + E_MAP0, wsI + E_LIST1, wsI + E_CNT, wsF + E_Y1);
  // level 2
  k_cnt2<<<dim3(NB2, BDIM), 256, 0, stream>>>(wsI + E_MAP1,
                                              wsI + E_BC + 2 * BDIM * 1024,
                                              bm + 2 * BDIM * 4096);
  k_scan<<<BDIM, 256, 0, stream>>>(wsI + E_BC + 2 * BDIM * 1024,
                                   wsI + E_BO + 2 * BDIM * 1024,
                                   wsI + E_CNT, NB2, 2 * BDIM);
  k_emit2<<<dim3(NB2, BDIM), 256, 0, stream>>>(bm + 2 * BDIM * 4096,
                                               wsI + E_BO + 2 * BDIM * 1024,
                                               wsI + E_LIST2);
  k_y2<<<BDIM * (CAPM / 32), 256, 0, stream>>>(
      wsF + E_Y1, w2, b2, g2, be2, wsI + E_MAP1, wsI + E_LIST2, wsI + E_CNT, wsF + E_FE);

  for (int layer = 0; layer < 2; ++layer) {
    k_qkv<<<BDIM * (CAPM / 16), 256, 0, stream>>>(
        wsF + E_FE, wsI + E_LIST2, wsI + E_CNT, wpe, bpe, wq, bq, wk, bk, wv, bv,
        layer, qf, kf, vt);
    k_attn<<<BDIM * NHEADS * (CAPM / 16), 256, 0, stream>>>(
        qf, kf, vt, wsI + E_CNT, ob);
    k_proj<<<BDIM * (CAPM / 4), 256, 0, stream>>>(
        ob, wo, bo, wsI + E_CNT, layer, wsF + E_FE);
  }

  k_head<<<BDIM, 1024, 0, stream>>>(wsF + E_FE, wh, bh, wsI + E_CNT, (float*)d_out);
}